// Round 8
// baseline (424.372 us; speedup 1.0000x reference)
//
#include <hip/hip_runtime.h>
#include <hip/hip_bf16.h>

typedef float  f32x4  __attribute__((ext_vector_type(4)));
typedef __bf16 bf16x8 __attribute__((ext_vector_type(8)));

#define SCALE_QK 0.17677669529663687f  /* 32^-0.5 (reference uses DIM_HEAD) */

// B=131072, L=4, dim=256, inner=32, heads=4, dh=8
// rows = 524288 ; 16-row tiles = 32768 ; grid 1024 x 4 waves x 8 tiles
// JOURNAL:
//  - VGPR cap ~128 enforced regardless of launch bounds (r1..r6); exceed -> spill.
//  - vmcnt is ONE in-order counter: any per-tile global weight load's wait
//    drains the x prefetch (r7, -15%). Keep per-tile vmem = x-loads + stores ONLY;
//    all B-operands from LDS (lgkm domain).  [r1 structure = correct]
//  - Scalar stores cost +78MB write-amp (r1 615 vs r7 524 w/ float4 swapped stores).
//  - This round = r1 + swapped float4 stores + packed-bf16 weight prekernel.

template<int CTRL>
__device__ __forceinline__ float dpp_add(float x) {
  int xi = __builtin_bit_cast(int, x);
  int yi = __builtin_amdgcn_mov_dpp(xi, CTRL, 0xF, 0xF, true);
  return x + __builtin_bit_cast(float, yi);
}

// ---------- prekernel: pack frag-ordered bf16 weights into d_ws ----------
// item = f*64 + lane, f in [0,64): wsf[item*8 + j]
// f in [0,48): GEMM1 frag (kt=f/6, ct=f%6): col n=ct*16+c, k=kt*32+g*8+j
// f in [48,64): Wo frag ct=f-48: col n=ct*16+c, k=g*8+j
__global__ void pack_weights(const float* __restrict__ Wq, const float* __restrict__ Wkv,
                             const float* __restrict__ Wo, __bf16* __restrict__ wsf) {
  const int item = blockIdx.x * 256 + threadIdx.x;   // 4096 items
  const int f = item >> 6, lane = item & 63;
  const int g = lane >> 4, c = lane & 15;
  union { bf16x8 v; __bf16 h[8]; } vv;
  if (f < 48) {
    const int kt = f / 6, ct = f - kt * 6;
    const int n = ct * 16 + c;
    #pragma unroll
    for (int j = 0; j < 8; ++j) {
      const int k = kt * 32 + g * 8 + j;
      vv.h[j] = (__bf16)((n < 32) ? Wq[k * 32 + n] : Wkv[k * 64 + (n - 32)]);
    }
  } else {
    const int ct = f - 48;
    const int n = ct * 16 + c;
    #pragma unroll
    for (int j = 0; j < 8; ++j) vv.h[j] = (__bf16)Wo[(g * 8 + j) * 256 + n];
  }
  *(bf16x8*)&wsf[item * 8] = vv.v;
}

#define FR(f) (*(const bf16x8*)&wfrag[(f)][lane][0])
#define MFMA(a, b, cc) __builtin_amdgcn_mfma_f32_16x16x32_bf16((a), (b), (cc), 0, 0, 0)

__global__ __launch_bounds__(256, 2) void fused_stattn(
    const float* __restrict__ x, const __bf16* __restrict__ wsf,
    const float* __restrict__ bo, const float* __restrict__ pe,
    float* __restrict__ out) {
  __shared__ __align__(16) __bf16 wfrag[64][64][8];   // 64 KiB (all frags)
  __shared__ __align__(16) __bf16 ao_lds[4][16][40];  // per-wave bounce
  __shared__ __align__(16) float bo_lds[256];
  __shared__ float pe_lds[64];

  const int tid  = threadIdx.x;
  const int lane = tid & 63;
  const int wv   = tid >> 6;
  const int g    = lane >> 4;   // 16-lane group
  const int c    = lane & 15;   // col within fragment / A-row

  // prologue: packed weights ws -> LDS (4096 x 16B chunks), bo, pe
  #pragma unroll
  for (int it = 0; it < 16; ++it) {
    const int idx = it * 256 + tid;
    *(bf16x8*)&wfrag[0][0][idx * 8] = *(const bf16x8*)&wsf[idx * 8];
  }
  bo_lds[tid] = bo[tid];
  if (tid < 64) pe_lds[tid] = pe[tid];
  __syncthreads();

  // ---------------- main loop: 8 tiles per wave ----------------
  const int slot  = blockIdx.x * 4 + wv;      // 0..4095
  const int tile0 = slot * 8;
  const f32x4* xv = (const f32x4*)x;          // row stride = 64 float4s

  f32x4 xbuf[16];
  {
    const int base = (tile0 * 16 + c) * 64 + g * 2;
    #pragma unroll
    for (int kt = 0; kt < 8; ++kt) {
      xbuf[2*kt]   = xv[base + kt*8];
      xbuf[2*kt+1] = xv[base + kt*8 + 1];
    }
  }

  for (int t = 0; t < 8; ++t) {
    const int tile  = tile0 + t;
    const int ntile = (tile + 1 < 32768) ? tile + 1 : tile;   // clamp last global tile
    const int nbase = (ntile * 16 + c) * 64 + g * 2;

    // ---- GEMM1: x[16x256] @ Wqkv[256x96]; interleaved next-tile x prefetch ----
    f32x4 acc0 = {0,0,0,0}, acc1 = {0,0,0,0}, acc2 = {0,0,0,0};
    f32x4 acc3 = {0,0,0,0}, acc4 = {0,0,0,0}, acc5 = {0,0,0,0};
    #pragma unroll
    for (int kt = 0; kt < 8; ++kt) {
      union { bf16x8 v; __bf16 h[8]; } af;    // A-frag: row=c, k = kt*32 + g*8 + j
      #pragma unroll
      for (int j = 0; j < 4; ++j) {
        af.h[j]   = (__bf16)xbuf[2*kt][j];
        af.h[4+j] = (__bf16)xbuf[2*kt+1][j];
      }
      // prefetch next tile's k-slab into the just-consumed slots
      xbuf[2*kt]   = xv[nbase + kt*8];
      xbuf[2*kt+1] = xv[nbase + kt*8 + 1];

      acc0 = MFMA(af.v, FR(kt*6+0), acc0);
      acc1 = MFMA(af.v, FR(kt*6+1), acc1);
      acc2 = MFMA(af.v, FR(kt*6+2), acc2);
      acc3 = MFMA(af.v, FR(kt*6+3), acc3);
      acc4 = MFMA(af.v, FR(kt*6+4), acc4);
      acc5 = MFMA(af.v, FR(kt*6+5), acc5);
    }
    // C layout: lane(g,c) reg i -> row g*4+i (batch g, seq i), col c. q/k/v pairs.

    // ---- attention (in registers; 8-lane head-dim reduce via DPP) ----
    const int h0 = c >> 3;
    float ao0[4], ao1[4];
    #pragma unroll
    for (int p = 0; p < 2; ++p) {
      const f32x4 qa = p ? acc1 : acc0;
      const f32x4 ka = p ? acc3 : acc2;
      const f32x4 va = p ? acc5 : acc4;
      const int ph = 2 * p + h0;              // head owning cols p*16 + c
      float sim[4][4];
      #pragma unroll
      for (int i = 0; i < 4; ++i)
        #pragma unroll
        for (int j = 0; j < 4; ++j) {
          float pr = qa[i] * ka[j];
          pr = dpp_add<0xB1>(pr);             // quad_perm xor1
          pr = dpp_add<0x4E>(pr);             // quad_perm xor2
          pr = dpp_add<0x141>(pr);            // row_half_mirror
          sim[i][j] = pr * SCALE_QK + pe_lds[ph * 16 + i * 4 + j];
        }
      #pragma unroll
      for (int i = 0; i < 4; ++i) {
        const float m = fmaxf(fmaxf(sim[i][0], sim[i][1]), fmaxf(sim[i][2], sim[i][3]));
        const float e0 = __expf(sim[i][0] - m), e1 = __expf(sim[i][1] - m);
        const float e2 = __expf(sim[i][2] - m), e3 = __expf(sim[i][3] - m);
        const float rs = 1.0f / (e0 + e1 + e2 + e3);
        const float o  = (e0*va[0] + e1*va[1] + e2*va[2] + e3*va[3]) * rs;
        if (p) ao1[i] = o; else ao0[i] = o;
      }
    }

    // ---- bounce C-layout -> B-frag layout for GEMM2 (per-wave private) ----
    #pragma unroll
    for (int i = 0; i < 4; ++i) {
      ao_lds[wv][g*4 + i][c]      = (__bf16)ao0[i];
      ao_lds[wv][g*4 + i][16 + c] = (__bf16)ao1[i];
    }
    const bf16x8 a2 = *(const bf16x8*)&ao_lds[wv][c][g * 8];  // col=c(=x-row), k=g*8+j

    // ---- GEMM2 (swapped): Wo^T @ ao^T, bias as C-input, float4 stores ----
    // D: lane(g,c) reg i -> out col ct*16 + g*4 + i, x-row c.
    const int orow = (tile * 16 + c) * 256;
    #pragma unroll
    for (int ct = 0; ct < 16; ++ct) {
      const f32x4 bv = *(const f32x4*)&bo_lds[ct * 16 + g * 4];
      f32x4 o = MFMA(FR(48 + ct), a2, bv);
      *(f32x4*)&out[orow + ct * 16 + g * 4] = o;
    }
  }
}

extern "C" void kernel_launch(void* const* d_in, const int* in_sizes, int n_in,
                              void* d_out, int out_size, void* d_ws, size_t ws_size,
                              hipStream_t stream) {
  const float* x   = (const float*)d_in[0];
  const float* Wq  = (const float*)d_in[1];
  const float* Wkv = (const float*)d_in[2];
  const float* Wo  = (const float*)d_in[3];
  const float* bo  = (const float*)d_in[4];
  const float* pe  = (const float*)d_in[5];
  float* out = (float*)d_out;
  __bf16* wsf = (__bf16*)d_ws;   // 64 KiB of frag-ordered bf16 weights

  hipLaunchKernelGGL(pack_weights, dim3(16), dim3(256), 0, stream, Wq, Wkv, Wo, wsf);
  hipLaunchKernelGGL(fused_stattn, dim3(1024), dim3(256), 0, stream,
                     x, wsf, bo, pe, out);
}

// Round 9
// 232.259 us; speedup vs baseline: 1.8272x; 1.8272x over previous
//
#include <hip/hip_runtime.h>
#include <hip/hip_bf16.h>

typedef float  f32x4  __attribute__((ext_vector_type(4)));
typedef __bf16 bf16x8 __attribute__((ext_vector_type(8)));

#define SCALE_QK 0.17677669529663687f  /* 32^-0.5 (reference uses DIM_HEAD) */

// B=131072, L=4, dim=256, inner=32, heads=4, dh=8
// rows = 524288 ; 16-row tiles = 32768 ; grid 1024 x 4 waves x 8 tiles
// JOURNAL:
//  - VGPR cap law (fits r1-r8): cap = 256 / (2nd launch_bounds arg).
//    (512,4)->64, (256,3)->84(~85), (256,2)->128. Exceed -> scratch spill
//    (tell: FETCH/WRITE balloon, dur +30-100%). This round: (256,1) -> cap 256.
//  - vmcnt is ONE in-order counter: per-tile global weight loads drain the x
//    prefetch (r7). Keep per-tile vmem = x-loads + stores ONLY; weights in LDS.
//  - Swapped GEMM2 (bias-as-C, float4 stores) = clean 524MB WRITE (r7), but
//    LICM hoists 16 f32x4 bias regs -> needs the 256 cap (r8 spilled at 128).
//  - Occupancy binds at LDS: 72KiB -> 2 blocks/CU = 8 waves/CU = 2 waves/SIMD,
//    legal up to 256 VGPR. (256,1) does not reduce residency.

template<int CTRL>
__device__ __forceinline__ float dpp_add(float x) {
  int xi = __builtin_bit_cast(int, x);
  int yi = __builtin_amdgcn_mov_dpp(xi, CTRL, 0xF, 0xF, true);
  return x + __builtin_bit_cast(float, yi);
}

// ---------- prekernel: pack frag-ordered bf16 weights into d_ws ----------
// item = f*64 + lane, f in [0,64): wsf[item*8 + j]
// f in [0,48): GEMM1 frag (kt=f/6, ct=f%6): col n=ct*16+c, k=kt*32+g*8+j
// f in [48,64): Wo frag ct=f-48: col n=ct*16+c, k=g*8+j
__global__ void pack_weights(const float* __restrict__ Wq, const float* __restrict__ Wkv,
                             const float* __restrict__ Wo, __bf16* __restrict__ wsf) {
  const int item = blockIdx.x * 256 + threadIdx.x;   // 4096 items
  const int f = item >> 6, lane = item & 63;
  const int g = lane >> 4, c = lane & 15;
  union { bf16x8 v; __bf16 h[8]; } vv;
  if (f < 48) {
    const int kt = f / 6, ct = f - kt * 6;
    const int n = ct * 16 + c;
    #pragma unroll
    for (int j = 0; j < 8; ++j) {
      const int k = kt * 32 + g * 8 + j;
      vv.h[j] = (__bf16)((n < 32) ? Wq[k * 32 + n] : Wkv[k * 64 + (n - 32)]);
    }
  } else {
    const int ct = f - 48;
    const int n = ct * 16 + c;
    #pragma unroll
    for (int j = 0; j < 8; ++j) vv.h[j] = (__bf16)Wo[(g * 8 + j) * 256 + n];
  }
  *(bf16x8*)&wsf[item * 8] = vv.v;
}

#define FR(f) (*(const bf16x8*)&wfrag[(f)][lane][0])
#define MFMA(a, b, cc) __builtin_amdgcn_mfma_f32_16x16x32_bf16((a), (b), (cc), 0, 0, 0)

__global__ __launch_bounds__(256, 1) void fused_stattn(
    const float* __restrict__ x, const __bf16* __restrict__ wsf,
    const float* __restrict__ bo, const float* __restrict__ pe,
    float* __restrict__ out) {
  __shared__ __align__(16) __bf16 wfrag[64][64][8];   // 64 KiB (all frags)
  __shared__ __align__(16) __bf16 ao_lds[4][16][40];  // per-wave bounce
  __shared__ __align__(16) float bo_lds[256];
  __shared__ float pe_lds[64];

  const int tid  = threadIdx.x;
  const int lane = tid & 63;
  const int wv   = tid >> 6;
  const int g    = lane >> 4;   // 16-lane group
  const int c    = lane & 15;   // col within fragment / A-row

  // prologue: packed weights ws -> LDS (4096 x 16B chunks), bo, pe
  #pragma unroll
  for (int it = 0; it < 16; ++it) {
    const int idx = it * 256 + tid;
    *(bf16x8*)&wfrag[0][0][idx * 8] = *(const bf16x8*)&wsf[idx * 8];
  }
  bo_lds[tid] = bo[tid];
  if (tid < 64) pe_lds[tid] = pe[tid];
  __syncthreads();

  // ---------------- main loop: 8 tiles per wave ----------------
  const int slot  = blockIdx.x * 4 + wv;      // 0..4095
  const int tile0 = slot * 8;
  const f32x4* xv = (const f32x4*)x;          // row stride = 64 float4s

  f32x4 xbuf[16];
  {
    const int base = (tile0 * 16 + c) * 64 + g * 2;
    #pragma unroll
    for (int kt = 0; kt < 8; ++kt) {
      xbuf[2*kt]   = xv[base + kt*8];
      xbuf[2*kt+1] = xv[base + kt*8 + 1];
    }
  }

  for (int t = 0; t < 8; ++t) {
    const int tile  = tile0 + t;
    const int ntile = (tile + 1 < 32768) ? tile + 1 : tile;   // clamp last global tile
    const int nbase = (ntile * 16 + c) * 64 + g * 2;

    // ---- GEMM1: x[16x256] @ Wqkv[256x96]; interleaved next-tile x prefetch ----
    f32x4 acc0 = {0,0,0,0}, acc1 = {0,0,0,0}, acc2 = {0,0,0,0};
    f32x4 acc3 = {0,0,0,0}, acc4 = {0,0,0,0}, acc5 = {0,0,0,0};
    #pragma unroll
    for (int kt = 0; kt < 8; ++kt) {
      union { bf16x8 v; __bf16 h[8]; } af;    // A-frag: row=c, k = kt*32 + g*8 + j
      #pragma unroll
      for (int j = 0; j < 4; ++j) {
        af.h[j]   = (__bf16)xbuf[2*kt][j];
        af.h[4+j] = (__bf16)xbuf[2*kt+1][j];
      }
      // prefetch next tile's k-slab into the just-consumed slots
      xbuf[2*kt]   = xv[nbase + kt*8];
      xbuf[2*kt+1] = xv[nbase + kt*8 + 1];

      acc0 = MFMA(af.v, FR(kt*6+0), acc0);
      acc1 = MFMA(af.v, FR(kt*6+1), acc1);
      acc2 = MFMA(af.v, FR(kt*6+2), acc2);
      acc3 = MFMA(af.v, FR(kt*6+3), acc3);
      acc4 = MFMA(af.v, FR(kt*6+4), acc4);
      acc5 = MFMA(af.v, FR(kt*6+5), acc5);
    }
    // C layout: lane(g,c) reg i -> row g*4+i (batch g, seq i), col c. q/k/v pairs.

    // ---- attention (in registers; 8-lane head-dim reduce via DPP) ----
    const int h0 = c >> 3;
    float ao0[4], ao1[4];
    #pragma unroll
    for (int p = 0; p < 2; ++p) {
      const f32x4 qa = p ? acc1 : acc0;
      const f32x4 ka = p ? acc3 : acc2;
      const f32x4 va = p ? acc5 : acc4;
      const int ph = 2 * p + h0;              // head owning cols p*16 + c
      float sim[4][4];
      #pragma unroll
      for (int i = 0; i < 4; ++i)
        #pragma unroll
        for (int j = 0; j < 4; ++j) {
          float pr = qa[i] * ka[j];
          pr = dpp_add<0xB1>(pr);             // quad_perm xor1
          pr = dpp_add<0x4E>(pr);             // quad_perm xor2
          pr = dpp_add<0x141>(pr);            // row_half_mirror
          sim[i][j] = pr * SCALE_QK + pe_lds[ph * 16 + i * 4 + j];
        }
      #pragma unroll
      for (int i = 0; i < 4; ++i) {
        const float m = fmaxf(fmaxf(sim[i][0], sim[i][1]), fmaxf(sim[i][2], sim[i][3]));
        const float e0 = __expf(sim[i][0] - m), e1 = __expf(sim[i][1] - m);
        const float e2 = __expf(sim[i][2] - m), e3 = __expf(sim[i][3] - m);
        const float rs = 1.0f / (e0 + e1 + e2 + e3);
        const float o  = (e0*va[0] + e1*va[1] + e2*va[2] + e3*va[3]) * rs;
        if (p) ao1[i] = o; else ao0[i] = o;
      }
    }

    // ---- bounce C-layout -> B-frag layout for GEMM2 (per-wave private) ----
    #pragma unroll
    for (int i = 0; i < 4; ++i) {
      ao_lds[wv][g*4 + i][c]      = (__bf16)ao0[i];
      ao_lds[wv][g*4 + i][16 + c] = (__bf16)ao1[i];
    }
    const bf16x8 a2 = *(const bf16x8*)&ao_lds[wv][c][g * 8];  // col=c(=x-row), k=g*8+j

    // ---- GEMM2 (swapped): Wo^T @ ao^T, bias as C-input, float4 stores ----
    // D: lane(g,c) reg i -> out col ct*16 + g*4 + i, x-row c.
    const int orow = (tile * 16 + c) * 256;
    #pragma unroll
    for (int ct = 0; ct < 16; ++ct) {
      const f32x4 bv = *(const f32x4*)&bo_lds[ct * 16 + g * 4];
      f32x4 o = MFMA(FR(48 + ct), a2, bv);
      *(f32x4*)&out[orow + ct * 16 + g * 4] = o;
    }
  }
}

extern "C" void kernel_launch(void* const* d_in, const int* in_sizes, int n_in,
                              void* d_out, int out_size, void* d_ws, size_t ws_size,
                              hipStream_t stream) {
  const float* x   = (const float*)d_in[0];
  const float* Wq  = (const float*)d_in[1];
  const float* Wkv = (const float*)d_in[2];
  const float* Wo  = (const float*)d_in[3];
  const float* bo  = (const float*)d_in[4];
  const float* pe  = (const float*)d_in[5];
  float* out = (float*)d_out;
  __bf16* wsf = (__bf16*)d_ws;   // 64 KiB of frag-ordered bf16 weights

  hipLaunchKernelGGL(pack_weights, dim3(16), dim3(256), 0, stream, Wq, Wkv, Wo, wsf);
  hipLaunchKernelGGL(fused_stattn, dim3(1024), dim3(256), 0, stream,
                     x, wsf, bo, pe, out);
}